// Round 5
// baseline (39.913 us; speedup 1.0000x reference)
//
#include <hip/hip_runtime.h>
#include <hip/hip_bf16.h>

// Problem: B=16, N=256, F=64, H=64
// out[b,i,j] = (i==j) ? 1 : sigmoid( sum_h relu(a[b,i,h]+c[b,j,h]) * w2[h] + b2 )
// where a = hs @ w1[:, :64]^T + b1, c = hs @ w1[:, 64:]^T
//
// Single fused kernel, plain launch. Each block (b, i-tile32, j-tile32)
// recomputes its a/c tiles from hs+w1 (x8 redundant phase-1, ~+1us VALU) --
// no workspace round-trip, no second kernel node, no grid sync.

#define Fd 64
#define Hd 64
#define Nn 256

__global__ __launch_bounds__(256) void fused_kernel(
    const float* __restrict__ hs, const float* __restrict__ w1,
    const float* __restrict__ b1, const float* __restrict__ w2,
    const float* __restrict__ b2, float* __restrict__ out) {
  // aT4/cT4 hold staged hs rows during phase 1, then a/c results for phase 2.
  __shared__ float4 aT4[32][16];
  __shared__ float4 cT4[32][16];
  __shared__ float4 w2s4[16];

  const int t  = threadIdx.x;
  const int b  = blockIdx.z;
  const int i0 = blockIdx.y * 32;
  const int j0 = blockIdx.x * 32;

  // ---- Stage hs tiles. Phase-1 swizzle: col = f4 ^ ((r>>2)&3) ----
  {
    const float4* hsi4 = (const float4*)(hs + (size_t)(b * Nn + i0) * Fd);
    const float4* hsj4 = (const float4*)(hs + (size_t)(b * Nn + j0) * Fd);
#pragma unroll
    for (int p = 0; p < 2; ++p) {
      const int k = t + 256 * p;       // 0..511
      const int r = k >> 4, f4 = k & 15;
      const int cs = f4 ^ ((r >> 2) & 3);
      aT4[r][cs] = hsi4[k];
      cT4[r][cs] = hsj4[k];
    }
    if (t < 16) w2s4[t] = ((const float4*)w2)[t];
  }
  __syncthreads();

  // ---- Phase 1: waves 0-1 -> a-tile (from hs_i), waves 2-3 -> c-tile ----
  const bool isA = (t < 128);                 // wave-uniform
  const int bidx = t & 127;
  const int m    = bidx >> 4;                 // r-block 0..7
  const int l    = bidx & 15;                 // h-block 0..15

  const float4 (*hsrc)[16] = isA ? aT4 : cT4;
  const float* w1p = w1 + (isA ? 0 : Fd);     // a-part / c-part column offset

  float accv[4][4];
#pragma unroll
  for (int kr = 0; kr < 4; ++kr)
#pragma unroll
    for (int kh = 0; kh < 4; ++kh) accv[kr][kh] = 0.f;

#pragma unroll
  for (int f4 = 0; f4 < 16; ++f4) {
    float4 hv[4], wv[4];
#pragma unroll
    for (int k = 0; k < 4; ++k)
      hv[k] = hsrc[m * 4 + k][f4 ^ (m & 3)];  // conflict-free (swizzled)
#pragma unroll
    for (int k = 0; k < 4; ++k)
      wv[k] = ((const float4*)(w1p + (size_t)(l * 4 + k) * (2 * Fd)))[f4];
#pragma unroll
    for (int kr = 0; kr < 4; ++kr)
#pragma unroll
      for (int kh = 0; kh < 4; ++kh) {
        accv[kr][kh] = fmaf(hv[kr].x, wv[kh].x, accv[kr][kh]);
        accv[kr][kh] = fmaf(hv[kr].y, wv[kh].y, accv[kr][kh]);
        accv[kr][kh] = fmaf(hv[kr].z, wv[kh].z, accv[kr][kh]);
        accv[kr][kh] = fmaf(hv[kr].w, wv[kh].w, accv[kr][kh]);
      }
  }

  float4 res[4];
#pragma unroll
  for (int kr = 0; kr < 4; ++kr) {
    res[kr].x = accv[kr][0]; res[kr].y = accv[kr][1];
    res[kr].z = accv[kr][2]; res[kr].w = accv[kr][3];
  }
  if (isA) {
    const float4 bb = ((const float4*)b1)[l];
#pragma unroll
    for (int kr = 0; kr < 4; ++kr) {
      res[kr].x += bb.x; res[kr].y += bb.y;
      res[kr].z += bb.z; res[kr].w += bb.w;
    }
  }

  __syncthreads();   // everyone done READING staged hs

  // Overwrite with a/c results using the phase-2 swizzle: col = q ^ (r&15)
  {
    float4 (*dst)[16] = isA ? aT4 : cT4;
#pragma unroll
    for (int kr = 0; kr < 4; ++kr) {
      const int r = m * 4 + kr;
      dst[r][l ^ (r & 15)] = res[kr];
    }
  }
  __syncthreads();

  // ---- Phase 2: pairwise logits + sigmoid (r3 body) ----
  const float bias2 = b2[0];
  const int jj  = t & 31;
  const int ii0 = (t >> 5) << 2;

  float acc0 = 0.f, acc1 = 0.f, acc2 = 0.f, acc3 = 0.f;
#pragma unroll
  for (int h4 = 0; h4 < 16; ++h4) {
    const float4 cc = cT4[jj][h4 ^ (jj & 15)];
    const float4 ww = w2s4[h4];
    const float4 a0 = aT4[ii0 + 0][h4 ^ ((ii0 + 0) & 15)];
    const float4 a1 = aT4[ii0 + 1][h4 ^ ((ii0 + 1) & 15)];
    const float4 a2 = aT4[ii0 + 2][h4 ^ ((ii0 + 2) & 15)];
    const float4 a3 = aT4[ii0 + 3][h4 ^ ((ii0 + 3) & 15)];

    acc0 = fmaf(fmaxf(a0.x + cc.x, 0.f), ww.x, acc0);
    acc0 = fmaf(fmaxf(a0.y + cc.y, 0.f), ww.y, acc0);
    acc0 = fmaf(fmaxf(a0.z + cc.z, 0.f), ww.z, acc0);
    acc0 = fmaf(fmaxf(a0.w + cc.w, 0.f), ww.w, acc0);

    acc1 = fmaf(fmaxf(a1.x + cc.x, 0.f), ww.x, acc1);
    acc1 = fmaf(fmaxf(a1.y + cc.y, 0.f), ww.y, acc1);
    acc1 = fmaf(fmaxf(a1.z + cc.z, 0.f), ww.z, acc1);
    acc1 = fmaf(fmaxf(a1.w + cc.w, 0.f), ww.w, acc1);

    acc2 = fmaf(fmaxf(a2.x + cc.x, 0.f), ww.x, acc2);
    acc2 = fmaf(fmaxf(a2.y + cc.y, 0.f), ww.y, acc2);
    acc2 = fmaf(fmaxf(a2.z + cc.z, 0.f), ww.z, acc2);
    acc2 = fmaf(fmaxf(a2.w + cc.w, 0.f), ww.w, acc2);

    acc3 = fmaf(fmaxf(a3.x + cc.x, 0.f), ww.x, acc3);
    acc3 = fmaf(fmaxf(a3.y + cc.y, 0.f), ww.y, acc3);
    acc3 = fmaf(fmaxf(a3.z + cc.z, 0.f), ww.z, acc3);
    acc3 = fmaf(fmaxf(a3.w + cc.w, 0.f), ww.w, acc3);
  }

  const int j = j0 + jj;
  float accs[4] = {acc0, acc1, acc2, acc3};
#pragma unroll
  for (int u = 0; u < 4; ++u) {
    const int i = i0 + ii0 + u;
    const float logit = accs[u] + bias2;
    const float s = 1.f / (1.f + __expf(-logit));
    out[(size_t)(b * Nn + i) * Nn + j] = (i == j) ? 1.0f : s;
  }
}

extern "C" void kernel_launch(void* const* d_in, const int* in_sizes, int n_in,
                              void* d_out, int out_size, void* d_ws, size_t ws_size,
                              hipStream_t stream) {
  const float* hs = (const float*)d_in[0];
  const float* w1 = (const float*)d_in[1];
  const float* b1 = (const float*)d_in[2];
  const float* w2 = (const float*)d_in[3];
  const float* b2 = (const float*)d_in[4];
  float* out = (float*)d_out;

  dim3 grid(Nn / 32, Nn / 32, 16);   // (j-tiles, i-tiles, b) = 1024 blocks
  fused_kernel<<<grid, 256, 0, stream>>>(hs, w1, b1, w2, b2, out);
}

// Round 6
// 22.120 us; speedup vs baseline: 1.8044x; 1.8044x over previous
//
#include <hip/hip_runtime.h>
#include <hip/hip_bf16.h>

// Problem: B=16, N=256, F=64, H=64
// out[b,i,j] = (i==j) ? 1 : sigmoid( sum_h relu(a[b,i,h]+c[b,j,h]) * w2[h] + b2 )
// a = hs @ w1[:, :64]^T + b1, c = hs @ w1[:, 64:]^T
//
// Round-6 theory: previous kernels were stalled on scattered w1 global reads
// (64 distinct 512B-strided cache lines per wave-instruction). Prep v2 keeps
// w1 reads to 4 lines/instr; pair v2 uses 4x4 register blocking to cut LDS
// instruction count 2x per output.

#define Nn 256
#define Fd 64
#define Hd 64

// ---------------- prep: a = hs@w1a^T + b1, c = hs@w1c^T ----------------
// grid (4096/16, 4): block = 16 rows x 32 houts (hout in [0,128): a then c).
// thread = (row r = t&15, h-pair hl = (t>>4)*2). Within a wave only 4
// distinct w1 rows per load instruction -> 4 cache lines (was 64).
__global__ __launch_bounds__(256) void prep_kernel(
    const float* __restrict__ hs, const float* __restrict__ w1,
    const float* __restrict__ b1,
    float* __restrict__ a_, float* __restrict__ c_) {
  __shared__ float4 hs4s[16][16];

  const int t  = threadIdx.x;
  const int r0 = blockIdx.x * 16;
  const int hout0 = blockIdx.y * 32;

  // stage 16 hs rows (4 KB contiguous, coalesced), swizzle col = f4 ^ r
  {
    const int rr = t >> 4, ff = t & 15;
    hs4s[rr][ff ^ rr] = ((const float4*)(hs + (size_t)r0 * Fd))[t];
  }
  __syncthreads();

  const int r  = t & 15;
  const int hl = (t >> 4) * 2;
  const bool isA = (hout0 < Hd);                 // block-uniform
  const int hA = hout0 + hl - (isA ? 0 : Hd);    // w1 row index 0..62
  const float* w1base = w1 + (isA ? 0 : Fd);
  const float4* w1r0 = (const float4*)(w1base + (size_t)(hA + 0) * (2 * Fd));
  const float4* w1r1 = (const float4*)(w1base + (size_t)(hA + 1) * (2 * Fd));

  float acc0 = 0.f, acc1 = 0.f;
#pragma unroll
  for (int f4 = 0; f4 < 16; ++f4) {
    const float4 x  = hs4s[r][f4 ^ r];   // 2-way (free) LDS broadcast
    const float4 u0 = w1r0[f4];          // 4 distinct rows per wave-instr
    const float4 u1 = w1r1[f4];
    acc0 = fmaf(x.x, u0.x, acc0); acc0 = fmaf(x.y, u0.y, acc0);
    acc0 = fmaf(x.z, u0.z, acc0); acc0 = fmaf(x.w, u0.w, acc0);
    acc1 = fmaf(x.x, u1.x, acc1); acc1 = fmaf(x.y, u1.y, acc1);
    acc1 = fmaf(x.z, u1.z, acc1); acc1 = fmaf(x.w, u1.w, acc1);
  }

  float2 res;
  if (isA) {
    res.x = acc0 + b1[hA];
    res.y = acc1 + b1[hA + 1];
    *(float2*)(a_ + (size_t)(r0 + r) * Hd + hA) = res;
  } else {
    res.x = acc0; res.y = acc1;
    *(float2*)(c_ + (size_t)(r0 + r) * Hd + hA) = res;
  }
}

// ---------------- pair: 64x64 tile, 256 threads, 16 outputs/thread ----------------
// thread (it = t>>4, jt = t&15) owns i = i0+it*4+u, j = j0+jt*4+v.
// Swizzle col = q ^ ((row>>2)&15):
//   c-reads: 16 distinct rows (row>>2 = jt) -> 16 cols -> 2-way (free)
//   a-reads: 4 distinct rows (row>>2 = it) -> 4 distinct quads, broadcast-dedup
__global__ __launch_bounds__(256) void pair_kernel(
    const float* __restrict__ a_, const float* __restrict__ c_,
    const float* __restrict__ w2, const float* __restrict__ b2,
    float* __restrict__ out) {
  __shared__ float4 aT4[64][16];
  __shared__ float4 cT4[64][16];
  __shared__ float4 w2s4[16];

  const int t  = threadIdx.x;
  const int b  = blockIdx.z;
  const int i0 = blockIdx.y * 64;
  const int j0 = blockIdx.x * 64;

  // stage 64x64 a- and c-tiles (16 KB each), coalesced, swizzled
#pragma unroll
  for (int p = 0; p < 4; ++p) {
    const int k = t + 256 * p;           // 0..1023
    const int rr = k >> 4, q = k & 15;
    const int cs = q ^ ((rr >> 2) & 15);
    aT4[rr][cs] = ((const float4*)(a_ + (size_t)(b * Nn + i0) * Hd))[k];
    cT4[rr][cs] = ((const float4*)(c_ + (size_t)(b * Nn + j0) * Hd))[k];
  }
  if (t < 16) w2s4[t] = ((const float4*)w2)[t];
  __syncthreads();

  const int it = t >> 4;
  const int jt = t & 15;
  const int ib = it * 4;
  const int jb = jt * 4;

  float acc[4][4];
#pragma unroll
  for (int u = 0; u < 4; ++u)
#pragma unroll
    for (int v = 0; v < 4; ++v) acc[u][v] = 0.f;

#pragma unroll
  for (int h4 = 0; h4 < 16; ++h4) {
    const float4 ww = w2s4[h4];
    float4 aa[4], cc[4];
#pragma unroll
    for (int u = 0; u < 4; ++u) aa[u] = aT4[ib + u][h4 ^ it];
#pragma unroll
    for (int v = 0; v < 4; ++v) cc[v] = cT4[jb + v][h4 ^ jt];

#pragma unroll
    for (int u = 0; u < 4; ++u)
#pragma unroll
      for (int v = 0; v < 4; ++v) {
        acc[u][v] = fmaf(fmaxf(aa[u].x + cc[v].x, 0.f), ww.x, acc[u][v]);
        acc[u][v] = fmaf(fmaxf(aa[u].y + cc[v].y, 0.f), ww.y, acc[u][v]);
        acc[u][v] = fmaf(fmaxf(aa[u].z + cc[v].z, 0.f), ww.z, acc[u][v]);
        acc[u][v] = fmaf(fmaxf(aa[u].w + cc[v].w, 0.f), ww.w, acc[u][v]);
      }
  }

  const float bias2 = b2[0];
#pragma unroll
  for (int u = 0; u < 4; ++u) {
    const int i = i0 + ib + u;
    float4 o;
    {
      const float s0 = 1.f / (1.f + __expf(-(acc[u][0] + bias2)));
      const float s1 = 1.f / (1.f + __expf(-(acc[u][1] + bias2)));
      const float s2 = 1.f / (1.f + __expf(-(acc[u][2] + bias2)));
      const float s3 = 1.f / (1.f + __expf(-(acc[u][3] + bias2)));
      o.x = (i == j0 + jb + 0) ? 1.0f : s0;
      o.y = (i == j0 + jb + 1) ? 1.0f : s1;
      o.z = (i == j0 + jb + 2) ? 1.0f : s2;
      o.w = (i == j0 + jb + 3) ? 1.0f : s3;
    }
    // coalesced: 16 consecutive float4 per 16-lane group
    ((float4*)(out + (size_t)(b * Nn + i) * Nn + j0))[jt] = o;
  }
}

extern "C" void kernel_launch(void* const* d_in, const int* in_sizes, int n_in,
                              void* d_out, int out_size, void* d_ws, size_t ws_size,
                              hipStream_t stream) {
  const float* hs = (const float*)d_in[0];
  const float* w1 = (const float*)d_in[1];
  const float* b1 = (const float*)d_in[2];
  const float* w2 = (const float*)d_in[3];
  const float* b2 = (const float*)d_in[4];
  float* out = (float*)d_out;

  float* a_ws = (float*)d_ws;                  // 4096*64 floats = 1 MB
  float* c_ws = a_ws + (size_t)4096 * Hd;      // 1 MB

  dim3 pgrid(4096 / 16, 4);                    // 1024 blocks
  prep_kernel<<<pgrid, 256, 0, stream>>>(hs, w1, b1, a_ws, c_ws);

  dim3 qgrid(Nn / 64, Nn / 64, 16);            // 256 blocks = 1/CU
  pair_kernel<<<qgrid, 256, 0, stream>>>(a_ws, c_ws, w2, b2, out);
}